// Round 1
// baseline (792.095 us; speedup 1.0000x reference)
//
#include <hip/hip_runtime.h>
#include <hip/hip_bf16.h>
#include <math.h>

// Sizes
#define S 12
#define C 32
#define T 7
#define L2T 24            // 2*S tokens
#define H 16
#define D 32
#define DH 512            // H*D
#define GIN 12240         // S*S*(T*S+1)
#define GOUT 4608         // S*S*C
#define WC 128            // W*C
#define EPS 1e-5f

// ---------------- prep: build gi[3][12240] ----------------
__global__ __launch_bounds__(256) void k_prep(
    const float* __restrict__ it, const float* __restrict__ is_,
    const float* __restrict__ s2w, const float* __restrict__ s2b,
    float* __restrict__ gi)
{
    int idx = blockIdx.x * 256 + threadIdx.x;
    if (idx >= 3 * GIN) return;
    int i = idx / GIN, rem = idx % GIN;
    int ab = rem / 85, e = rem % 85;
    int a = ab / S, b = ab % S;
    float val;
    if (e < 84) {
        int k = e / T, t = e % T;
        int x, y, z;
        if (i == 0)      { x = a; y = b; z = k; }   // input_t[t,a,b,k]
        else if (i == 1) { x = b; y = k; z = a; }   // input_t[t,b,c,a]
        else             { x = k; y = a; z = b; }   // input_t[t,c,a,b]
        val = it[((t * S + x) * S + y) * S + z];
    } else {
        float acc = s2b[i * 144 + ab];
        const float* wr = s2w + (i * 144 + ab) * 8;
        #pragma unroll
        for (int u = 0; u < 8; u++) acc += wr[u] * is_[u];
        val = acc;
    }
    gi[idx] = val;
}

// ---------------- g2g: x[i] = W[i] @ gi[i] + b[i], one wave per row ----------------
__global__ __launch_bounds__(256) void k_g2g(
    const float* __restrict__ W, const float* __restrict__ gb,
    const float* __restrict__ gi, float* __restrict__ xbuf)
{
    int wave = threadIdx.x >> 6;
    int lane = threadIdx.x & 63;
    int r = blockIdx.x * 4 + wave;          // 0..13823
    int i = r / GOUT, rr = r % GOUT;
    const float4* Wr = reinterpret_cast<const float4*>(W + (size_t)r * GIN);
    const float4* gv = reinterpret_cast<const float4*>(gi + i * GIN);
    float acc = 0.f;
    for (int k = lane; k < GIN / 4; k += 64) {
        float4 w4 = Wr[k];
        float4 g4 = gv[k];
        acc += w4.x * g4.x + w4.y * g4.y + w4.z * g4.z + w4.w * g4.w;
    }
    #pragma unroll
    for (int off = 32; off; off >>= 1) acc += __shfl_down(acc, off, 64);
    if (lane == 0) xbuf[i * (2 * GOUT) + rr] = acc + gb[r];   // parity 0
}

// ---------------- K1: per (slice, head): LN + QKV + scores + O + W1 partial ----------------
__global__ __launch_bounds__(256) void k_attn_heads(
    const float* __restrict__ xm1, const float* __restrict__ xm2,
    const float* __restrict__ lnxg, const float* __restrict__ lnxb,
    const float* __restrict__ lnyg, const float* __restrict__ lnyb,
    const float* __restrict__ wqw, const float* __restrict__ wqb,
    const float* __restrict__ wkw, const float* __restrict__ wkb,
    const float* __restrict__ wvw, const float* __restrict__ wvb,
    const float* __restrict__ l1w,
    float* __restrict__ xpart, int l)
{
    int s = blockIdx.x >> 4, h = blockIdx.x & 15;
    int tid = threadIdx.x;
    __shared__ float a[768], xn[768], yn[768], q[768], kk[768], vv[768], o[768];
    __shared__ float sc[576];
    __shared__ float red[16];

    // load a = [x[m1][s] ; x[m2][:,s]]
    for (int idx = tid; idx < 768; idx += 256) {
        int r = idx >> 5, c = idx & 31;
        a[idx] = (r < S) ? xm1[s * 384 + r * 32 + c]
                         : xm2[(r - S) * 384 + s * 32 + c];
    }
    __syncthreads();

    // full-matrix LN stats (shared by xn and yn)
    float s1 = 0.f, s2 = 0.f;
    for (int idx = tid; idx < 768; idx += 256) { float z = a[idx]; s1 += z; s2 += z * z; }
    #pragma unroll
    for (int off = 32; off; off >>= 1) { s1 += __shfl_down(s1, off, 64); s2 += __shfl_down(s2, off, 64); }
    int wv = tid >> 6;
    if ((tid & 63) == 0) { red[wv * 2] = s1; red[wv * 2 + 1] = s2; }
    __syncthreads();
    if (tid == 0) {
        float t1 = red[0] + red[2] + red[4] + red[6];
        float t2 = red[1] + red[3] + red[5] + red[7];
        float mu = t1 * (1.f / 768.f);
        float var = t2 * (1.f / 768.f) - mu * mu;
        red[8] = mu;
        red[9] = rsqrtf(var + EPS);
    }
    __syncthreads();
    float mu = red[8], rs = red[9];

    int ls = l * S + s;
    const float* gx = lnxg + ls * 768; const float* bx = lnxb + ls * 768;
    const float* gy = lnyg + ls * 768; const float* by = lnyb + ls * 768;
    for (int idx = tid; idx < 768; idx += 256) {
        float zn = (a[idx] - mu) * rs;
        xn[idx] = zn * gx[idx] + bx[idx];
        yn[idx] = zn * gy[idx] + by[idx];
    }
    __syncthreads();

    // qkv for head h
    const float* wq = wqw + (size_t)ls * 16384 + h * 1024;
    const float* wk = wkw + (size_t)ls * 16384 + h * 1024;
    const float* wvp = wvw + (size_t)ls * 16384 + h * 1024;
    const float* qb = wqb + ls * 512 + h * 32;
    const float* kb = wkb + ls * 512 + h * 32;
    const float* vb = wvb + ls * 512 + h * 32;
    for (int idx = tid; idx < 768; idx += 256) {
        int r = idx >> 5, j = idx & 31;
        const float* xr = xn + r * 32;
        const float* yr = yn + r * 32;
        const float* wqr = wq + j * 32;
        const float* wkr = wk + j * 32;
        const float* wvr = wvp + j * 32;
        float aq = qb[j], ak = kb[j], av = vb[j];
        #pragma unroll
        for (int c = 0; c < 32; c++) {
            aq += xr[c] * wqr[c];
            ak += yr[c] * wkr[c];
            av += yr[c] * wvr[c];
        }
        q[idx] = aq; kk[idx] = ak; vv[idx] = av;
    }
    __syncthreads();

    // scores (24x24), no softmax
    for (int idx = tid; idx < 576; idx += 256) {
        int r = idx / 24, j = idx % 24;
        const float* qr = q + r * 32;
        const float* kr = kk + j * 32;
        float acc = 0.f;
        #pragma unroll
        for (int c = 0; c < 32; c++) acc += qr[c] * kr[c];
        sc[idx] = acc * 0.17677669529663687f;   // 1/sqrt(32)
    }
    __syncthreads();

    // o_h = sc @ v  (24x32)
    for (int idx = tid; idx < 768; idx += 256) {
        int r = idx >> 5, c = idx & 31;
        const float* sr = sc + r * 24;
        float acc = 0.f;
        #pragma unroll
        for (int j = 0; j < 24; j++) acc += sr[j] * vv[j * 32 + c];
        o[idx] = acc;
    }
    __syncthreads();

    // xpart = o_h @ w1_h^T  (24x32), w1_h = l1_w[:, h*32:(h+1)*32]
    const float* w1 = l1w + (size_t)ls * 16384 + h * 32;
    float* xp = xpart + (s * 16 + h) * 768;
    for (int idx = tid; idx < 768; idx += 256) {
        int r = idx >> 5, j = idx & 31;
        const float* orow = o + r * 32;
        const float* w1r = w1 + j * 512;
        float acc = 0.f;
        #pragma unroll
        for (int c = 0; c < 32; c++) acc += orow[c] * w1r[c];
        xp[idx] = acc;
    }
}

// ---------------- K2: reduce heads + residual + LN + FFN, write new buffers ----------------
__global__ __launch_bounds__(256) void k_ffn(
    const float* __restrict__ xm1, const float* __restrict__ xm2,
    const float* __restrict__ xpart,
    const float* __restrict__ l1b,
    const float* __restrict__ lnfg, const float* __restrict__ lnfb,
    const float* __restrict__ l2w, const float* __restrict__ l2b,
    const float* __restrict__ l3w, const float* __restrict__ l3b,
    float* __restrict__ out_m1, float* __restrict__ out_m2, int l)
{
    int s = blockIdx.x;
    int tid = threadIdx.x;
    __shared__ float x[768], hn[768], g[3072];
    __shared__ float red[16];
    int ls = l * S + s;
    const float* b1 = l1b + ls * 32;

    for (int idx = tid; idx < 768; idx += 256) {
        int r = idx >> 5, c = idx & 31;
        float av = (r < S) ? xm1[s * 384 + r * 32 + c]
                           : xm2[(r - S) * 384 + s * 32 + c];
        float acc = av + b1[c];
        const float* xp = xpart + s * 16 * 768 + idx;
        #pragma unroll
        for (int hh = 0; hh < 16; hh++) acc += xp[hh * 768];
        x[idx] = acc;
    }
    __syncthreads();

    float s1 = 0.f, s2 = 0.f;
    for (int idx = tid; idx < 768; idx += 256) { float z = x[idx]; s1 += z; s2 += z * z; }
    #pragma unroll
    for (int off = 32; off; off >>= 1) { s1 += __shfl_down(s1, off, 64); s2 += __shfl_down(s2, off, 64); }
    int wv = tid >> 6;
    if ((tid & 63) == 0) { red[wv * 2] = s1; red[wv * 2 + 1] = s2; }
    __syncthreads();
    if (tid == 0) {
        float t1 = red[0] + red[2] + red[4] + red[6];
        float t2 = red[1] + red[3] + red[5] + red[7];
        float mu = t1 * (1.f / 768.f);
        float var = t2 * (1.f / 768.f) - mu * mu;
        red[8] = mu;
        red[9] = rsqrtf(var + EPS);
    }
    __syncthreads();
    float mu = red[8], rs = red[9];

    const float* gf = lnfg + ls * 768; const float* bf = lnfb + ls * 768;
    for (int idx = tid; idx < 768; idx += 256)
        hn[idx] = (x[idx] - mu) * rs * gf[idx] + bf[idx];
    __syncthreads();

    // g = gelu(hn @ w2^T + b2)  (24x128), exact gelu
    const float* w2 = l2w + (size_t)ls * 4096;
    const float* b2 = l2b + ls * 128;
    for (int idx = tid; idx < 3072; idx += 256) {
        int r = idx >> 7, u = idx & 127;
        const float* hr = hn + r * 32;
        const float* w2r = w2 + u * 32;
        float acc = b2[u];
        #pragma unroll
        for (int c = 0; c < 32; c++) acc += hr[c] * w2r[c];
        g[idx] = acc * 0.5f * (1.f + erff(acc * 0.70710678118654752f));
    }
    __syncthreads();

    // out = x + g @ w3^T + b3, write rows to the new buffers
    const float* w3 = l3w + (size_t)ls * 4096;
    const float* b3 = l3b + ls * 32;
    for (int idx = tid; idx < 768; idx += 256) {
        int r = idx >> 5, j = idx & 31;
        const float* gr = g + r * 128;
        const float* w3r = w3 + j * 128;
        float acc = x[idx] + b3[j];
        #pragma unroll
        for (int u = 0; u < 128; u++) acc += gr[u] * w3r[u];
        if (r < S) out_m1[s * 384 + r * 32 + j] = acc;
        else       out_m2[s * 384 + (r - S) * 32 + j] = acc;
    }
}

// ---------------- pack: out[(a*3+i)*12+b][c] = x_i[a][b][c] ----------------
__global__ __launch_bounds__(256) void k_pack(
    const float* __restrict__ x0, const float* __restrict__ x1,
    const float* __restrict__ x2, float* __restrict__ out)
{
    int idx = blockIdx.x * 256 + threadIdx.x;
    if (idx >= 3 * 144 * 32) return;
    int c = idx & 31;
    int r = idx >> 5;          // (a*3+i)*12 + b
    int b = r % 12;
    int ai = r / 12;
    int i = ai % 3;
    int a = ai / 3;
    const float* xs = (i == 0) ? x0 : ((i == 1) ? x1 : x2);
    out[idx] = xs[a * 384 + b * 32 + c];
}

extern "C" void kernel_launch(void* const* d_in, const int* in_sizes, int n_in,
                              void* d_out, int out_size, void* d_ws, size_t ws_size,
                              hipStream_t stream) {
    const float* input_t = (const float*)d_in[0];
    const float* input_s = (const float*)d_in[1];
    const float* s2g_w   = (const float*)d_in[2];
    const float* s2g_b   = (const float*)d_in[3];
    const float* g2g_w   = (const float*)d_in[4];
    const float* g2g_b   = (const float*)d_in[5];
    const float* lnx_g   = (const float*)d_in[6];
    const float* lnx_b   = (const float*)d_in[7];
    const float* lny_g   = (const float*)d_in[8];
    const float* lny_b   = (const float*)d_in[9];
    const float* lnf_g   = (const float*)d_in[10];
    const float* lnf_b   = (const float*)d_in[11];
    const float* wq_w    = (const float*)d_in[12];
    const float* wq_b    = (const float*)d_in[13];
    const float* wk_w    = (const float*)d_in[14];
    const float* wk_b    = (const float*)d_in[15];
    const float* wv_w    = (const float*)d_in[16];
    const float* wv_b    = (const float*)d_in[17];
    const float* l1_w    = (const float*)d_in[18];
    const float* l1_b    = (const float*)d_in[19];
    const float* l2_w    = (const float*)d_in[20];
    const float* l2_b    = (const float*)d_in[21];
    const float* l3_w    = (const float*)d_in[22];
    const float* l3_b    = (const float*)d_in[23];

    float* ws = (float*)d_ws;
    float* gi    = ws;                       // 3*12240 = 36720
    float* xbuf  = ws + 36720;               // 3*2*4608 = 27648
    float* xpart = ws + 36720 + 27648;       // 12*16*768 = 147456

    k_prep<<<144, 256, 0, stream>>>(input_t, input_s, s2g_w, s2g_b, gi);
    k_g2g<<<3456, 256, 0, stream>>>(g2g_w, g2g_b, gi, xbuf);

    int par[3] = {0, 0, 0};
    const int pairs[3][2] = {{0, 1}, {2, 0}, {1, 2}};
    for (int l = 0; l < 8; l++) {
        for (int pp = 0; pp < 3; pp++) {
            int m1 = pairs[pp][0], m2 = pairs[pp][1];
            float* in1  = xbuf + m1 * 9216 + par[m1] * 4608;
            float* in2  = xbuf + m2 * 9216 + par[m2] * 4608;
            float* out1 = xbuf + m1 * 9216 + (1 - par[m1]) * 4608;
            float* out2 = xbuf + m2 * 9216 + (1 - par[m2]) * 4608;
            k_attn_heads<<<192, 256, 0, stream>>>(in1, in2,
                lnx_g, lnx_b, lny_g, lny_b,
                wq_w, wq_b, wk_w, wk_b, wv_w, wv_b,
                l1_w, xpart, l);
            k_ffn<<<12, 256, 0, stream>>>(in1, in2, xpart, l1_b,
                lnf_g, lnf_b, l2_w, l2_b, l3_w, l3_b,
                out1, out2, l);
            par[m1] ^= 1; par[m2] ^= 1;
        }
    }
    k_pack<<<54, 256, 0, stream>>>(
        xbuf + 0 * 9216 + par[0] * 4608,
        xbuf + 1 * 9216 + par[1] * 4608,
        xbuf + 2 * 9216 + par[2] * 4608,
        (float*)d_out);
}